// Round 1
// baseline (357.131 us; speedup 1.0000x reference)
//
#include <hip/hip_runtime.h>

#define B_TOT   4096
#define T_STEPS 512
#define IN_F    5
#define D_FC    32
#define D_H     64
#define MB      8       // batches per block (rows remapped across quads; 8 of 16 M-rows valid)
#define NROW    16      // MFMA M-tile rows staged in LDS
#define ROWPAD  72      // f16 elems per row (64 h + 8 pad; rows = 144B, 16B-aligned)

typedef _Float16 h8 __attribute__((ext_vector_type(8)));
typedef float    f4 __attribute__((ext_vector_type(4)));

__device__ __forceinline__ float fexp2(float x) { return __builtin_amdgcn_exp2f(x); }
__device__ __forceinline__ float frcp(float x)  { return __builtin_amdgcn_rcpf(x); }
__device__ __forceinline__ float fsig(float x) {
    return frcp(1.0f + fexp2(-1.4426950408889634f * x));
}
__device__ __forceinline__ float ftanh(float x) {
    float e = fexp2(2.8853900817779268f * x);   // exp(2x); saturates at +-inf
    return 1.0f - 2.0f * frcp(e + 1.0f);
}

// batch b (0..7) -> M-tile row: quads 0..3 each hold 2 valid rows (regs 0,1)
__device__ __forceinline__ int mrow(int b) { return ((b >> 1) << 2) | (b & 1); }

__global__ __launch_bounds__(256) void lstm_mfma(
    const float* __restrict__ x,
    const float* __restrict__ W0,
    const float* __restrict__ b0,
    const float* __restrict__ W_ih,
    const float* __restrict__ W_hh,
    const float* __restrict__ b_ih,
    const float* __restrict__ b_hh,
    const float* __restrict__ Wo,
    const float* __restrict__ bo,
    float* __restrict__ out)
{
    // double-buffered h(t-1), f16: [row = M-tile batch row][k = hidden 0..63]
    __shared__ _Float16 H[2][NROW][ROWPAD];

    const int tid  = threadIdx.x;
    const int lane = tid & 63;
    const int w    = tid >> 6;      // wave id: owns hidden j in [w*16, w*16+16)
    const int col  = lane & 15;
    const int quad = lane >> 4;
    const int bblk = blockIdx.x * MB;

    // ---- resident W_hh B-fragments: lane holds gate q for j=w*16+col across K ----
    h8 Bf[4][2];
    #pragma unroll
    for (int q = 0; q < 4; ++q) {
        const int row = q * 64 + w * 16 + col;
        #pragma unroll
        for (int c = 0; c < 2; ++c) {
            h8 f;
            #pragma unroll
            for (int jj = 0; jj < 8; ++jj) {
                const int k = c * 32 + quad * 8 + jj;   // hidden index 0..63
                f[jj] = (_Float16)W_hh[row * D_H + k];
            }
            Bf[q][c] = f;
        }
    }

    // ---- folded x-side weights: Weff = W_ih * W0  (256 x 5), K=32-padded frag ----
    // nonzero only for quad==0 && jj<5; zero B-side guarantees dead K-lanes contribute 0
    h8 Bx[4];
    #pragma unroll
    for (int q = 0; q < 4; ++q) {
        const int row = q * 64 + w * 16 + col;
        h8 f;
        #pragma unroll
        for (int jj = 0; jj < 8; ++jj) f[jj] = (_Float16)0.0f;
        if (quad == 0) {
            #pragma unroll
            for (int jj = 0; jj < IN_F; ++jj) {
                float s = 0.0f;
                #pragma unroll
                for (int m = 0; m < D_FC; ++m)
                    s = fmaf(W_ih[row * D_FC + m], W0[m * IN_F + jj], s);
                f[jj] = (_Float16)s;
            }
        }
        Bx[q] = f;
    }

    // ---- folded bias: beff = b_ih + b_hh + W_ih * b0 ----
    float bias_q[4];
    #pragma unroll
    for (int q = 0; q < 4; ++q) {
        const int row = q * 64 + w * 16 + col;
        float s = b_ih[row] + b_hh[row];
        #pragma unroll
        for (int m = 0; m < D_FC; ++m)
            s = fmaf(W_ih[row * D_FC + m], b0[m], s);
        bias_q[q] = s;
    }

    // ---- zero both LDS buffers (covers garbage rows + pad) ----
    for (int i = tid; i < 2 * NROW * ROWPAD; i += 256)
        ((_Float16*)H)[i] = (_Float16)0.0f;

    // ---- x feed: A-frag M-row 'col' <-> batch 2*(col>>2)+(col&1)  (garbage rows dup a valid batch) ----
    const float* xb = x + (size_t)(bblk + 2 * (col >> 2) + (col & 1)) * T_STEPS * IN_F;
    float xr[IN_F];
    #pragma unroll
    for (int i = 0; i < IN_F; ++i) xr[i] = xb[i];          // x(0)
    h8 Ax;
    #pragma unroll
    for (int i = 0; i < IN_F; ++i) Ax[i] = (_Float16)xr[i];
    Ax[5] = Ax[6] = Ax[7] = (_Float16)0.0f;                // stays zero across iters
    #pragma unroll
    for (int i = 0; i < IN_F; ++i) xr[i] = xb[IN_F + i];   // prefetch x(1)

    // cell state: lane holds c for j=w*16+col, batches quad*2 + {0,1}
    float c_st[2] = {0.0f, 0.0f};

    __syncthreads();

    for (int t = 0; t < T_STEPS; ++t) {
        const int rp = t & 1, wp = rp ^ 1;

        // h(t-1) A-fragments (b128, 16B aligned)
        const h8 A1 = *(const h8*)&H[rp][col][quad * 8];
        const h8 A2 = *(const h8*)&H[rp][col][32 + quad * 8];

        f4 acc[4];
        #pragma unroll
        for (int q = 0; q < 4; ++q) {
            f4 a = { bias_q[q], bias_q[q], bias_q[q], bias_q[q] };
            // x-side MFMA: register-resident operands, independent of the LDS reads
            a = __builtin_amdgcn_mfma_f32_16x16x32_f16(Ax, Bx[q], a, 0, 0, 0);
            a = __builtin_amdgcn_mfma_f32_16x16x32_f16(A1, Bf[q][0], a, 0, 0, 0);
            a = __builtin_amdgcn_mfma_f32_16x16x32_f16(A2, Bf[q][1], a, 0, 0, 0);
            acc[q] = a;
        }

        // next-step x frag + prefetch x(t+2): vmem latency hides under elementwise
        #pragma unroll
        for (int i = 0; i < IN_F; ++i) Ax[i] = (_Float16)xr[i];
        const int tn = (t + 2 < T_STEPS) ? (t + 2) : (T_STEPS - 1);
        #pragma unroll
        for (int i = 0; i < IN_F; ++i) xr[i] = xb[tn * IN_F + i];

        // elementwise LSTM: every lane has rows quad*4 + {0,1} valid (2 updates)
        #pragma unroll
        for (int r = 0; r < 2; ++r) {
            const float ig = fsig(acc[0][r]);
            const float fg = fsig(acc[1][r]);
            const float g_ = ftanh(acc[2][r]);
            const float og = fsig(acc[3][r]);
            c_st[r] = fmaf(fg, c_st[r], ig * g_);
            const float hh = og * ftanh(c_st[r]);
            H[wp][quad * 4 + r][w * 16 + col] = (_Float16)hh;
        }

        __syncthreads();   // single barrier: writes to buf[wp] visible for next step
    }

    // ---- output head: h_last lives in H[T&1 = 0] ----
    if (tid < MB) {
        const int hr = mrow(tid);
        float a = bo[0];
        #pragma unroll 8
        for (int j = 0; j < D_H; ++j)
            a = fmaf((float)H[0][hr][j], Wo[j], a);
        out[bblk + tid] = a;
    }
}

extern "C" void kernel_launch(void* const* d_in, const int* in_sizes, int n_in,
                              void* d_out, int out_size, void* d_ws, size_t ws_size,
                              hipStream_t stream) {
    const float* x    = (const float*)d_in[0];
    const float* W0   = (const float*)d_in[1];
    const float* b0   = (const float*)d_in[2];
    const float* W_ih = (const float*)d_in[3];
    const float* W_hh = (const float*)d_in[4];
    const float* b_ih = (const float*)d_in[5];
    const float* b_hh = (const float*)d_in[6];
    const float* Wo   = (const float*)d_in[7];
    const float* bo   = (const float*)d_in[8];
    float* out = (float*)d_out;

    hipLaunchKernelGGL(lstm_mfma, dim3(B_TOT / MB), dim3(256), 0, stream,
                       x, W0, b0, W_ih, W_hh, b_ih, b_hh, Wo, bo, out);
}

// Round 2
// 342.134 us; speedup vs baseline: 1.0438x; 1.0438x over previous
//
#include <hip/hip_runtime.h>

#define B_TOT   4096
#define T_STEPS 512
#define IN_F    5
#define D_FC    32
#define D_H     64
#define MB      8       // batches per block (8 valid of 16 M-rows, remapped across quads)
#define NROW    16      // MFMA M-tile rows staged in LDS
#define ROWE    72      // f16 elems per row (64 h + 8 pad; 144B rows stay 16B-aligned)

typedef _Float16 h8 __attribute__((ext_vector_type(8)));
typedef __fp16   h2 __attribute__((ext_vector_type(2)));
typedef float    f4 __attribute__((ext_vector_type(4)));

__device__ __forceinline__ float fexp2(float x) { return __builtin_amdgcn_exp2f(x); }
__device__ __forceinline__ float frcp(float x)  { return __builtin_amdgcn_rcpf(x); }

// batch b (0..7) -> M-tile row: quads 0..3 each hold 2 valid rows (regs 0,1)
__device__ __forceinline__ int mrow(int b) { return ((b >> 1) << 2) | (b & 1); }

__global__ __launch_bounds__(256) void lstm_mfma(
    const float* __restrict__ x,
    const float* __restrict__ W0,
    const float* __restrict__ b0,
    const float* __restrict__ W_ih,
    const float* __restrict__ W_hh,
    const float* __restrict__ b_ih,
    const float* __restrict__ b_hh,
    const float* __restrict__ Wo,
    const float* __restrict__ bo,
    float* __restrict__ out)
{
    // double-buffered h(t-1), f16
    __shared__ __align__(16) _Float16 H[2][NROW][ROWE];

    const int tid  = threadIdx.x;
    const int lane = tid & 63;
    const int w    = tid >> 6;      // wave id: owns hidden j in [w*16, w*16+16)
    const int col  = lane & 15;
    const int quad = lane >> 4;
    const int bblk = blockIdx.x * MB;

    const float K1 = 1.4426950408889634f;   // log2(e)
    const float K2 = 2.8853900817779268f;   // 2*log2(e)

    // ---- resident W_hh B-fragments ----
    h8 Bf[4][2];
    #pragma unroll
    for (int q = 0; q < 4; ++q) {
        const int row = q * 64 + w * 16 + col;
        #pragma unroll
        for (int c = 0; c < 2; ++c) {
            h8 f;
            #pragma unroll
            for (int jj = 0; jj < 8; ++jj) {
                const int k = c * 32 + quad * 8 + jj;
                f[jj] = (_Float16)W_hh[row * D_H + k];
            }
            Bf[q][c] = f;
        }
    }

    // ---- folded x-side weights: Weff = W_ih * W0 (256 x 5), K=32-padded frag ----
    h8 Bx[4];
    #pragma unroll
    for (int q = 0; q < 4; ++q) {
        const int row = q * 64 + w * 16 + col;
        h8 f;
        #pragma unroll
        for (int jj = 0; jj < 8; ++jj) f[jj] = (_Float16)0.0f;
        if (quad == 0) {
            #pragma unroll
            for (int jj = 0; jj < IN_F; ++jj) {
                float s = 0.0f;
                #pragma unroll
                for (int m = 0; m < D_FC; ++m)
                    s = fmaf(W_ih[row * D_FC + m], W0[m * IN_F + jj], s);
                f[jj] = (_Float16)s;
            }
        }
        Bx[q] = f;
    }

    // ---- folded bias, pre-scaled into the exp2 argument (exact f32, zero per-step cost) ----
    float sb[4];
    #pragma unroll
    for (int q = 0; q < 4; ++q) {
        const int row = q * 64 + w * 16 + col;
        float s = b_ih[row] + b_hh[row];
        #pragma unroll
        for (int m = 0; m < D_FC; ++m)
            s = fmaf(W_ih[row * D_FC + m], b0[m], s);
        sb[q] = s;
    }
    const float nbi = -K1 * sb[0];
    const float nbf = -K1 * sb[1];
    const float pbg =  K2 * sb[2];
    const float nbo = -K1 * sb[3];

    // ---- zero both LDS buffers (h(-1)=0; garbage rows stay 0) ----
    for (int i = tid; i < 2 * NROW * ROWE; i += 256)
        ((_Float16*)H)[i] = (_Float16)0.0f;

    // ---- x feed: A-frag M-row 'col' <-> batch 2*(col>>2)+(col&1) ----
    const float* xb = x + (size_t)(bblk + 2 * (col >> 2) + (col & 1)) * T_STEPS * IN_F;

    union AxU { h8 v; h2 p[4]; };
    AxU Ax[2];
    #pragma unroll
    for (int jj = 0; jj < 8; ++jj) { Ax[0].v[jj] = (_Float16)0.0f; Ax[1].v[jj] = (_Float16)0.0f; }
    {   // Ax[0] = x(0)
        const f4 v0 = *(const f4*)xb;
        const float s0 = xb[4];
        Ax[0].p[0] = __builtin_amdgcn_cvt_pkrtz(v0[0], v0[1]);
        Ax[0].p[1] = __builtin_amdgcn_cvt_pkrtz(v0[2], v0[3]);
        Ax[0].p[2] = __builtin_amdgcn_cvt_pkrtz(s0, 0.0f);
    }
    // prefetch buffers: xv[0]=x(1), xv[1]=x(2)
    f4 xv[2]; float x4[2];
    xv[0] = *(const f4*)(xb + IN_F);      x4[0] = xb[IN_F + 4];
    xv[1] = *(const f4*)(xb + 2 * IN_F);  x4[1] = xb[2 * IN_F + 4];

    f4 zk = {0.0f, 0.0f, 0.0f, 0.0f};   // MFMA C-source (kept live; acc starts at zero)
    float cs[2] = {0.0f, 0.0f};

    __syncthreads();    // full barrier once: zero-init visible

    for (int it = 0; it < T_STEPS / 2; ++it) {
        #pragma unroll
        for (int u = 0; u < 2; ++u) {
            // h(t-1) A-fragments from buffer u (base VGPR + imm offsets after unroll)
            const h8 A1 = *(const h8*)&H[u][col][quad * 8];
            const h8 A2 = *(const h8*)&H[u][col][32 + quad * 8];

            // pack next-step Ax while lgkm pending; then issue x(t+3) prefetch
            Ax[u ^ 1].p[0] = __builtin_amdgcn_cvt_pkrtz(xv[u][0], xv[u][1]);
            Ax[u ^ 1].p[1] = __builtin_amdgcn_cvt_pkrtz(xv[u][2], xv[u][3]);
            Ax[u ^ 1].p[2] = __builtin_amdgcn_cvt_pkrtz(x4[u], 0.0f);
            {
                int tn = 2 * it + u + 3;
                tn = (tn < T_STEPS) ? tn : (T_STEPS - 1);
                const float* xp = xb + tn * IN_F;
                xv[u] = *(const f4*)xp;     // stays in flight across the barrier (no vmcnt drain)
                x4[u] = xp[4];
            }

            f4 acc[4];
            #pragma unroll
            for (int q = 0; q < 4; ++q) {
                f4 a = __builtin_amdgcn_mfma_f32_16x16x32_f16(Ax[u].v, Bx[q], zk, 0, 0, 0);
                a = __builtin_amdgcn_mfma_f32_16x16x32_f16(A1, Bf[q][0], a, 0, 0, 0);
                a = __builtin_amdgcn_mfma_f32_16x16x32_f16(A2, Bf[q][1], a, 0, 0, 0);
                acc[q] = a;
            }

            // elementwise LSTM: rows quad*4 + {0,1} valid; bias folded into fma constants
            #pragma unroll
            for (int r = 0; r < 2; ++r) {
                const float ig = frcp(1.0f + fexp2(fmaf(-K1, acc[0][r], nbi)));
                const float fg = frcp(1.0f + fexp2(fmaf(-K1, acc[1][r], nbf)));
                const float eg = fexp2(fmaf(K2, acc[2][r], pbg));
                const float gg = fmaf(-2.0f, frcp(eg + 1.0f), 1.0f);
                const float og = frcp(1.0f + fexp2(fmaf(-K1, acc[3][r], nbo)));
                cs[r] = fmaf(fg, cs[r], ig * gg);
                const float ec = fexp2(K2 * cs[r]);
                const float th = fmaf(-2.0f, frcp(ec + 1.0f), 1.0f);
                H[u ^ 1][quad * 4 + r][w * 16 + col] = (_Float16)(og * th);
            }

            // barrier WITHOUT vmcnt(0) drain: LDS writes visible, x-prefetch stays in flight
            asm volatile("s_waitcnt lgkmcnt(0)" ::: "memory");
            __builtin_amdgcn_s_barrier();
            asm volatile("" ::: "memory");
        }
    }

    // ---- output head: h_last lives in H[0] (t=511 wrote buffer 0) ----
    if (tid < MB) {
        const int hr = mrow(tid);
        float a = bo[0];
        #pragma unroll 8
        for (int j = 0; j < D_H; ++j)
            a = fmaf((float)H[0][hr][j], Wo[j], a);
        out[bblk + tid] = a;
    }
}

extern "C" void kernel_launch(void* const* d_in, const int* in_sizes, int n_in,
                              void* d_out, int out_size, void* d_ws, size_t ws_size,
                              hipStream_t stream) {
    const float* x    = (const float*)d_in[0];
    const float* W0   = (const float*)d_in[1];
    const float* b0   = (const float*)d_in[2];
    const float* W_ih = (const float*)d_in[3];
    const float* W_hh = (const float*)d_in[4];
    const float* b_ih = (const float*)d_in[5];
    const float* b_hh = (const float*)d_in[6];
    const float* Wo   = (const float*)d_in[7];
    const float* bo   = (const float*)d_in[8];
    float* out = (float*)d_out;

    hipLaunchKernelGGL(lstm_mfma, dim3(B_TOT / MB), dim3(256), 0, stream,
                       x, W0, b0, W_ih, W_hh, b_ih, b_hh, Wo, bo, out);
}